// Round 3
// baseline (9128.203 us; speedup 1.0000x reference)
//
#include <hip/hip_runtime.h>

#define N 128
#define PAD2 129
#define NL 8128
#define POWER_IT 18
#define INV_IT 8
#define NTHREADS 512
#define SMEM_BYTES 137248

// LDS layout (doubles):
//   Ad[128*129]  native fp64 matrix (132096 B)
//   dinvd[128]   1/U[k,k]
//   dmisc[4]     [0]=lmax, [1..3]=lmin per inverse wave
//   fX4[128] float4, fW4[128] float4 (power-iteration vectors)

static __device__ __forceinline__ float hashf(unsigned x) {
    x ^= 2747636419u; x *= 2654435769u; x ^= x >> 16;
    x *= 2654435769u; x ^= x >> 16; x *= 2654435769u;
    return ((float)(x >> 8)) * (1.0f / 16777216.0f) - 0.5f;
}
static __device__ __forceinline__ double readlane_d(double x, int lane) {
    int lo = __builtin_amdgcn_readlane(__double2loint(x), lane);
    int hi = __builtin_amdgcn_readlane(__double2hiint(x), lane);
    return __hiloint2double(hi, lo);
}

// Cholesky of 4x4 Gram (packed upper, 10) -> C = R^{-1} (upper, row-major 4x4)
static __device__ __forceinline__ void cholInvC(const double* Gp, double* C) {
    double g[4][4];
    int c = 0;
    #pragma unroll
    for (int a = 0; a < 4; ++a)
        #pragma unroll
        for (int b2 = a; b2 < 4; ++b2) { g[a][b2] = Gp[c]; g[b2][a] = Gp[c]; ++c; }
    double R[4][4];
    #pragma unroll
    for (int i = 0; i < 4; ++i) {
        double d = g[i][i];
        #pragma unroll
        for (int m = 0; m < 4; ++m) if (m < i) d -= R[m][i] * R[m][i];
        d = sqrt(fmax(d, 1e-300));
        R[i][i] = d;
        #pragma unroll
        for (int j = 0; j < 4; ++j) if (j > i) {
            double v = g[i][j];
            #pragma unroll
            for (int m = 0; m < 4; ++m) if (m < i) v -= R[m][i] * R[m][j];
            R[i][j] = v / d;
        }
    }
    #pragma unroll
    for (int j = 3; j >= 0; --j) {
        C[j*4 + j] = 1.0 / R[j][j];
        #pragma unroll
        for (int i = 3; i >= 0; --i) if (i < j) {
            double v = 0.0;
            #pragma unroll
            for (int m = 0; m < 4; ++m) if (m > i && m <= j) v += R[i][m] * C[m*4 + j];
            C[i*4 + j] = -v / R[i][i];
        }
        #pragma unroll
        for (int i = 0; i < 4; ++i) if (i > j) C[i*4 + j] = 0.0;
    }
}

static __device__ __forceinline__ double jacobi4_lmax(const double* Gp) {
    double g[4][4];
    int c = 0;
    #pragma unroll
    for (int a = 0; a < 4; ++a)
        #pragma unroll
        for (int b2 = a; b2 < 4; ++b2) { g[a][b2] = Gp[c]; g[b2][a] = Gp[c]; ++c; }
    #pragma unroll
    for (int sweep = 0; sweep < 6; ++sweep) {
        #pragma unroll
        for (int p = 0; p < 3; ++p) {
            #pragma unroll
            for (int q = p + 1; q < 4; ++q) {
                double apq = g[p][q];
                double tau = (g[q][q] - g[p][p]) / (2.0 * apq);
                double t = (tau >= 0.0 ? 1.0 : -1.0) / (fabs(tau) + sqrt(1.0 + tau * tau));
                if (fabs(apq) < 1e-280) t = 0.0;
                double cc = 1.0 / sqrt(1.0 + t * t);
                double ss = t * cc;
                #pragma unroll
                for (int r = 0; r < 4; ++r) {
                    double grp = g[r][p], grq = g[r][q];
                    g[r][p] = cc * grp - ss * grq;
                    g[r][q] = ss * grp + cc * grq;
                }
                #pragma unroll
                for (int r = 0; r < 4; ++r) {
                    double gpr = g[p][r], gqr = g[q][r];
                    g[p][r] = cc * gpr - ss * gqr;
                    g[q][r] = ss * gpr + cc * gqr;
                }
            }
        }
    }
    return fmax(fmax(g[0][0], g[1][1]), fmax(g[2][2], g[3][3]));
}

static __device__ __forceinline__ void cholqr2_d(double ya[2], double yb[2]) {
    double g00 = ya[0]*ya[0] + yb[0]*yb[0];
    double g01 = ya[0]*ya[1] + yb[0]*yb[1];
    double g11 = ya[1]*ya[1] + yb[1]*yb[1];
    #pragma unroll
    for (int o = 32; o > 0; o >>= 1) {
        g00 += __shfl_xor(g00, o);
        g01 += __shfl_xor(g01, o);
        g11 += __shfl_xor(g11, o);
    }
    double r00 = sqrt(fmax(g00, 1e-300));
    double r01 = g01 / r00;
    double r11 = sqrt(fmax(g11 - r01 * r01, fabs(g11) * 1e-26 + 1e-300));
    double c00 = 1.0 / r00, c11 = 1.0 / r11;
    double c01 = -r01 * c00 * c11;
    double a0 = ya[0]*c00,             b0 = yb[0]*c00;
    double a1 = ya[0]*c01 + ya[1]*c11, b1 = yb[0]*c01 + yb[1]*c11;
    ya[0] = a0; yb[0] = b0; ya[1] = a1; yb[1] = b1;
}

#define FMA4(acc, a, v4) { acc[0] += (a)*(v4).x; acc[1] += (a)*(v4).y; acc[2] += (a)*(v4).z; acc[3] += (a)*(v4).w; }

__global__ __launch_bounds__(NTHREADS, 1)
void cond_kernel(const float* __restrict__ DD, const float* __restrict__ LE,
                 const float* __restrict__ SCL, double* __restrict__ conds)
{
    extern __shared__ char smraw[];
    double* Ad    = (double*)smraw;        // 16512
    double* dinvd = Ad + N * PAD2;         // 128
    double* dmisc = dinvd + 128;           // 4
    float4* fX4   = (float4*)(dmisc + 4);  // 128
    float4* fW4   = fX4 + 128;             // 128

    const int tid = threadIdx.x;
    const int b   = blockIdx.x;
    const int wid = tid >> 6;
    const int l   = tid & 63;
    const int rB  = l + 64;
    const double s = (double)SCL[0];
    const float* dd = DD + (size_t)b * (N * N);
    const float* le = LE + (size_t)b * NL;

    // ---- stage DD -> fp64
    for (int t = tid; t < (N * N) / 4; t += NTHREADS) {
        float4 dv = reinterpret_cast<const float4*>(dd)[t];
        int elem = t * 4;
        int i = elem >> 7, j = elem & 127;
        double* dst = &Ad[i * PAD2 + j];
        dst[0] = (double)dv.x; dst[1] = (double)dv.y;
        dst[2] = (double)dv.z; dst[3] = (double)dv.w;
    }
    __syncthreads();

    const int pr_ = tid >> 4;   // 0..31: row in 32-row block
    const int pc_ = tid & 15;   // col group: cols pc_+16e

    // ---- Pass A: T = D + s * E^T D (E = strict-lower le), ascending 32-row blocks
    for (int KB = 0; KB < N; KB += 32) {
        const int k = KB + pr_;
        double acc[8];
        #pragma unroll
        for (int e = 0; e < 8; ++e) acc[e] = 0.0;
        int off = (KB + 1) * KB / 2 + k;
        #pragma unroll 2
        for (int i = KB + 1; i < N; ++i) {
            int offs = (i > k) ? off : 0;
            float lef = le[offs];
            double lv = (i > k) ? (double)lef : 0.0;
            #pragma unroll
            for (int e = 0; e < 8; ++e) acc[e] += lv * Ad[i * PAD2 + pc_ + 16 * e];
            off += i;
        }
        __syncthreads();
        #pragma unroll
        for (int e = 0; e < 8; ++e) Ad[k * PAD2 + pc_ + 16 * e] += s * acc[e];
        __syncthreads();
    }

    // ---- Pass B: P = T + s * E T, descending 32-row blocks
    for (int IB = N - 32; IB >= 0; IB -= 32) {
        const int i = IB + pr_;
        const float* er = le + i * (i - 1) / 2;
        double acc[8];
        #pragma unroll
        for (int e = 0; e < 8; ++e) acc[e] = 0.0;
        #pragma unroll 2
        for (int m = 0; m < IB + 32; ++m) {
            int mm = (m < i) ? m : 0;
            float lef = er[mm];
            double lv = (m < i) ? (double)lef : 0.0;
            #pragma unroll
            for (int e = 0; e < 8; ++e) acc[e] += lv * Ad[m * PAD2 + pc_ + 16 * e];
        }
        __syncthreads();
        #pragma unroll
        for (int e = 0; e < 8; ++e) Ad[i * PAD2 + pc_ + 16 * e] += s * acc[e];
        __syncthreads();
    }

    // ---- LU with partial pivoting, in place, fp64
    for (int k = 0; k < N - 1; ++k) {
        if (wid == 0) {
            float v0 = (l >= k) ? (float)fabs(Ad[l * PAD2 + k]) : -1.0f;
            float v1 = (rB >= k) ? (float)fabs(Ad[rB * PAD2 + k]) : -1.0f;
            float vm = v0; int im = l;
            if (v1 > vm) { vm = v1; im = rB; }
            #pragma unroll
            for (int o = 32; o > 0; o >>= 1) {
                float ov = __shfl_xor(vm, o);
                int   oi = __shfl_xor(im, o);
                if (ov > vm) { vm = ov; im = oi; }
            }
            if (l == 0) dinvd[k] = 1.0 / Ad[im * PAD2 + k];
            if (im != k) {
                double t0 = Ad[k * PAD2 + l];
                Ad[k * PAD2 + l] = Ad[im * PAD2 + l];
                Ad[im * PAD2 + l] = t0;
                double t1 = Ad[k * PAD2 + rB];
                Ad[k * PAD2 + rB] = Ad[im * PAD2 + rB];
                Ad[im * PAD2 + rB] = t1;
            }
        }
        __syncthreads();
        double invd = dinvd[k];
        int g16 = tid >> 5, l32 = tid & 31;
        double ukj[4];
        #pragma unroll
        for (int m2 = 0; m2 < 4; ++m2) {
            int j = k + 1 + l32 + 32 * m2;
            ukj[m2] = (j < N) ? Ad[k * PAD2 + j] : 0.0;
        }
        #pragma unroll 2
        for (int i = k + 1 + g16; i < N; i += 16) {
            double lik = Ad[i * PAD2 + k] * invd;
            if (l32 == 0) Ad[i * PAD2 + k] = lik;
            #pragma unroll
            for (int m2 = 0; m2 < 4; ++m2) {
                int j = k + 1 + l32 + 32 * m2;
                if (j < N) Ad[i * PAD2 + j] -= lik * ukj[m2];
            }
        }
        __syncthreads();
    }
    if (tid == 0) dinvd[N - 1] = 1.0 / Ad[(N - 1) * PAD2 + (N - 1)];
    __syncthreads();

    // ================= concurrent iteration phase =================
    if (wid == 0) {
        // block-4 power on P^T P = U^T L^T L U (fp32, split-range triangular sweeps)
        #pragma unroll
        for (int h = 0; h < 2; ++h) {
            int r = l + 64 * h;
            float4 xv;
            xv.x = hashf(13u + (unsigned)r * 7919u);
            xv.y = hashf(14u + (unsigned)r * 7919u);
            xv.z = hashf(15u + (unsigned)r * 7919u);
            xv.w = hashf(16u + (unsigned)r * 7919u);
            fX4[r] = xv;
        }
        for (int it = 0; it < POWER_IT; ++it) {
            // t = U x
            float t0[4] = {0,0,0,0}, t1[4] = {0,0,0,0};
            #pragma unroll 2
            for (int j = 0; j < 64; ++j) {
                float a0 = (j >= l) ? (float)Ad[l * PAD2 + j] : 0.f;
                float4 xv = fX4[j];
                FMA4(t0, a0, xv);
            }
            #pragma unroll 2
            for (int j = 64; j < 128; ++j) {
                float a0 = (float)Ad[l * PAD2 + j];
                float a1 = (j >= rB) ? (float)Ad[rB * PAD2 + j] : 0.f;
                float4 xv = fX4[j];
                FMA4(t0, a0, xv); FMA4(t1, a1, xv);
            }
            fW4[l]  = make_float4(t0[0], t0[1], t0[2], t0[3]);
            fW4[rB] = make_float4(t1[0], t1[1], t1[2], t1[3]);
            // u = L t (unit diag)
            float u0[4] = {t0[0],t0[1],t0[2],t0[3]}, u1[4] = {t1[0],t1[1],t1[2],t1[3]};
            #pragma unroll 2
            for (int j = 0; j < 64; ++j) {
                float a0 = (j < l) ? (float)Ad[l * PAD2 + j] : 0.f;
                float a1 = (float)Ad[rB * PAD2 + j];
                float4 tv = fW4[j];
                FMA4(u0, a0, tv); FMA4(u1, a1, tv);
            }
            #pragma unroll 2
            for (int j = 64; j < 128; ++j) {
                float a1 = (j < rB) ? (float)Ad[rB * PAD2 + j] : 0.f;
                float4 tv = fW4[j];
                FMA4(u1, a1, tv);
            }
            fW4[l]  = make_float4(u0[0], u0[1], u0[2], u0[3]);
            fW4[rB] = make_float4(u1[0], u1[1], u1[2], u1[3]);
            // w = L^T u
            float w0[4] = {u0[0],u0[1],u0[2],u0[3]}, w1[4] = {u1[0],u1[1],u1[2],u1[3]};
            #pragma unroll 2
            for (int i = 0; i < 64; ++i) {
                float b0 = (i > l) ? (float)Ad[i * PAD2 + l] : 0.f;
                float4 uv = fW4[i];
                FMA4(w0, b0, uv);
            }
            #pragma unroll 2
            for (int i = 64; i < 128; ++i) {
                float b0 = (float)Ad[i * PAD2 + l];
                float b1 = (i > rB) ? (float)Ad[i * PAD2 + rB] : 0.f;
                float4 uv = fW4[i];
                FMA4(w0, b0, uv); FMA4(w1, b1, uv);
            }
            fW4[l]  = make_float4(w0[0], w0[1], w0[2], w0[3]);
            fW4[rB] = make_float4(w1[0], w1[1], w1[2], w1[3]);
            // z = U^T w
            float z0[4] = {0,0,0,0}, z1[4] = {0,0,0,0};
            #pragma unroll 2
            for (int i = 0; i < 64; ++i) {
                float c0 = (i <= l) ? (float)Ad[i * PAD2 + l] : 0.f;
                float c1 = (float)Ad[i * PAD2 + rB];
                float4 wv = fW4[i];
                FMA4(z0, c0, wv); FMA4(z1, c1, wv);
            }
            #pragma unroll 2
            for (int i = 64; i < 128; ++i) {
                float c1 = (i <= rB) ? (float)Ad[i * PAD2 + rB] : 0.f;
                float4 wv = fW4[i];
                FMA4(z1, c1, wv);
            }
            if ((it & 1) == 1) {
                // CholQR in fp64
                double pr2[10];
                { int c = 0;
                  #pragma unroll
                  for (int v = 0; v < 4; ++v)
                      #pragma unroll
                      for (int w2 = v; w2 < 4; ++w2) {
                          pr2[c] = (double)z0[v] * z0[w2] + (double)z1[v] * z1[w2]; ++c;
                      } }
                #pragma unroll
                for (int o = 32; o > 0; o >>= 1)
                    #pragma unroll
                    for (int c2 = 0; c2 < 10; ++c2) pr2[c2] += __shfl_xor(pr2[c2], o);
                double C[16];
                cholInvC(pr2, C);
                float xn0[4], xn1[4];
                #pragma unroll
                for (int v = 0; v < 4; ++v) {
                    double sa = 0.0, sb = 0.0;
                    #pragma unroll
                    for (int u2 = 0; u2 <= v; ++u2) {
                        sa += C[u2 * 4 + v] * (double)z0[u2];
                        sb += C[u2 * 4 + v] * (double)z1[u2];
                    }
                    xn0[v] = (float)sa; xn1[v] = (float)sb;
                }
                fX4[l]  = make_float4(xn0[0], xn0[1], xn0[2], xn0[3]);
                fX4[rB] = make_float4(xn1[0], xn1[1], xn1[2], xn1[3]);
            } else {
                float n2 = 0.f;
                #pragma unroll
                for (int v = 0; v < 4; ++v) n2 += z0[v]*z0[v] + z1[v]*z1[v];
                #pragma unroll
                for (int o = 32; o > 0; o >>= 1) n2 += __shfl_xor(n2, o);
                float inz = rsqrtf(n2 + 1e-30f);
                fX4[l]  = make_float4(z0[0]*inz, z0[1]*inz, z0[2]*inz, z0[3]*inz);
                fX4[rB] = make_float4(z1[0]*inz, z1[1]*inz, z1[2]*inz, z1[3]*inz);
            }
        }
        // Ritz for lambda_max: Z = L U x (x orthonormal)
        {
            float t0[4] = {0,0,0,0}, t1[4] = {0,0,0,0};
            #pragma unroll 2
            for (int j = 0; j < 64; ++j) {
                float a0 = (j >= l) ? (float)Ad[l * PAD2 + j] : 0.f;
                float4 xv = fX4[j];
                FMA4(t0, a0, xv);
            }
            #pragma unroll 2
            for (int j = 64; j < 128; ++j) {
                float a0 = (float)Ad[l * PAD2 + j];
                float a1 = (j >= rB) ? (float)Ad[rB * PAD2 + j] : 0.f;
                float4 xv = fX4[j];
                FMA4(t0, a0, xv); FMA4(t1, a1, xv);
            }
            fW4[l]  = make_float4(t0[0], t0[1], t0[2], t0[3]);
            fW4[rB] = make_float4(t1[0], t1[1], t1[2], t1[3]);
            float u0[4] = {t0[0],t0[1],t0[2],t0[3]}, u1[4] = {t1[0],t1[1],t1[2],t1[3]};
            #pragma unroll 2
            for (int j = 0; j < 64; ++j) {
                float a0 = (j < l) ? (float)Ad[l * PAD2 + j] : 0.f;
                float a1 = (float)Ad[rB * PAD2 + j];
                float4 tv = fW4[j];
                FMA4(u0, a0, tv); FMA4(u1, a1, tv);
            }
            #pragma unroll 2
            for (int j = 64; j < 128; ++j) {
                float a1 = (j < rB) ? (float)Ad[rB * PAD2 + j] : 0.f;
                float4 tv = fW4[j];
                FMA4(u1, a1, tv);
            }
            double pr2[10];
            { int c = 0;
              #pragma unroll
              for (int v = 0; v < 4; ++v)
                  #pragma unroll
                  for (int w2 = v; w2 < 4; ++w2) {
                      pr2[c] = (double)u0[v] * u0[w2] + (double)u1[v] * u1[w2]; ++c;
                  } }
            #pragma unroll
            for (int o = 32; o > 0; o >>= 1)
                #pragma unroll
                for (int c2 = 0; c2 < 10; ++c2) pr2[c2] += __shfl_xor(pr2[c2], o);
            double lmax = jacobi4_lmax(pr2);
            if (l == 0) dmisc[0] = lmax;
        }
    } else if (wid <= 3) {
        // 3 independent block-2 fp64 inverse iterations (waves 1..3)
        unsigned seed = 1013u * (unsigned)wid;
        double ya[2], yb[2];
        #pragma unroll
        for (int v = 0; v < 2; ++v) {
            ya[v] = (double)hashf(seed + (unsigned)(v * 337 + l * 101 + 7));
            yb[v] = (double)hashf(seed + (unsigned)(v * 337 + rB * 101 + 7));
        }
        for (int it = 0; it < INV_IT; ++it) {
            // (a) U^T a = y, forward
            #pragma unroll 4
            for (int i = 0; i < 64; ++i) {
                double invd = dinvd[i];
                double u0 = Ad[i * PAD2 + l];
                double u1 = Ad[i * PAD2 + rB];
                bool up0 = (l > i);
                #pragma unroll
                for (int v = 0; v < 2; ++v) {
                    double av = readlane_d(ya[v], i) * invd;
                    double upd = ya[v] - u0 * av;
                    ya[v] = (l == i) ? av : (up0 ? upd : ya[v]);
                    yb[v] -= u1 * av;
                }
            }
            #pragma unroll 4
            for (int i2 = 0; i2 < 64; ++i2) {
                double invd = dinvd[64 + i2];
                double u1 = Ad[(64 + i2) * PAD2 + rB];
                bool up1 = (l > i2);
                #pragma unroll
                for (int v = 0; v < 2; ++v) {
                    double av = readlane_d(yb[v], i2) * invd;
                    double upd = yb[v] - u1 * av;
                    yb[v] = (l == i2) ? av : (up1 ? upd : yb[v]);
                }
            }
            // (b) L^T b = a, backward (unit diag)
            #pragma unroll 4
            for (int j2 = 63; j2 >= 0; --j2) {
                int j = 64 + j2;
                double L0 = Ad[j * PAD2 + l];
                double L1 = Ad[j * PAD2 + rB];
                bool m1 = (l < j2);
                #pragma unroll
                for (int v = 0; v < 2; ++v) {
                    double bv = readlane_d(yb[v], j2);
                    ya[v] -= L0 * bv;
                    double upd = yb[v] - L1 * bv;
                    yb[v] = m1 ? upd : yb[v];
                }
            }
            #pragma unroll 4
            for (int j = 63; j >= 1; --j) {
                double L0 = Ad[j * PAD2 + l];
                bool m0 = (l < j);
                #pragma unroll
                for (int v = 0; v < 2; ++v) {
                    double bv = readlane_d(ya[v], j);
                    double upd = ya[v] - L0 * bv;
                    ya[v] = m0 ? upd : ya[v];
                }
            }
            // (c) L c = b, forward (unit diag)
            #pragma unroll 4
            for (int j = 0; j < 64; ++j) {
                double La0 = Ad[l * PAD2 + j];
                double La1 = Ad[rB * PAD2 + j];
                bool m0 = (l > j);
                #pragma unroll
                for (int v = 0; v < 2; ++v) {
                    double cv = readlane_d(ya[v], j);
                    double upd = ya[v] - La0 * cv;
                    ya[v] = m0 ? upd : ya[v];
                    yb[v] -= La1 * cv;
                }
            }
            #pragma unroll 4
            for (int j2 = 0; j2 < 64; ++j2) {
                double La1 = Ad[rB * PAD2 + 64 + j2];
                bool m1 = (l > j2);
                #pragma unroll
                for (int v = 0; v < 2; ++v) {
                    double cv = readlane_d(yb[v], j2);
                    double upd = yb[v] - La1 * cv;
                    yb[v] = m1 ? upd : yb[v];
                }
            }
            // (d) U x = c, backward
            #pragma unroll 4
            for (int i2 = 63; i2 >= 0; --i2) {
                int i = 64 + i2;
                double invd = dinvd[i];
                double U0 = Ad[l * PAD2 + i];
                double U1 = Ad[rB * PAD2 + i];
                bool m1 = (l < i2);
                #pragma unroll
                for (int v = 0; v < 2; ++v) {
                    double xv = readlane_d(yb[v], i2) * invd;
                    ya[v] -= U0 * xv;
                    double upd = yb[v] - U1 * xv;
                    yb[v] = (l == i2) ? xv : (m1 ? upd : yb[v]);
                }
            }
            #pragma unroll 4
            for (int i = 63; i >= 0; --i) {
                double invd = dinvd[i];
                double U0 = Ad[l * PAD2 + i];
                bool m0 = (l < i);
                #pragma unroll
                for (int v = 0; v < 2; ++v) {
                    double xv = readlane_d(ya[v], i) * invd;
                    double upd = ya[v] - U0 * xv;
                    ya[v] = (l == i) ? xv : (m0 ? upd : ya[v]);
                }
            }
            cholqr2_d(ya, yb);
            cholqr2_d(ya, yb);
        }
        // Ritz for lambda_min: z = L U y, 2x2 Gram
        double t0[2] = {0,0}, t1[2] = {0,0};
        #pragma unroll 4
        for (int j = 0; j < 64; ++j) {
            double u0 = Ad[l * PAD2 + j];
            u0 = (j >= l) ? u0 : 0.0;
            #pragma unroll
            for (int v = 0; v < 2; ++v) { double yj = readlane_d(ya[v], j); t0[v] += u0 * yj; }
        }
        #pragma unroll 4
        for (int j2 = 0; j2 < 64; ++j2) {
            int j = 64 + j2;
            double u0 = Ad[l * PAD2 + j];
            double u1 = Ad[rB * PAD2 + j];
            u1 = (j2 >= l) ? u1 : 0.0;
            #pragma unroll
            for (int v = 0; v < 2; ++v) {
                double yj = readlane_d(yb[v], j2);
                t0[v] += u0 * yj; t1[v] += u1 * yj;
            }
        }
        double z0[2] = {t0[0], t0[1]}, z1[2] = {t1[0], t1[1]};
        #pragma unroll 4
        for (int j = 0; j < 64; ++j) {
            double L0 = Ad[l * PAD2 + j];
            L0 = (j < l) ? L0 : 0.0;
            double L1 = Ad[rB * PAD2 + j];
            #pragma unroll
            for (int v = 0; v < 2; ++v) {
                double tj = readlane_d(t0[v], j);
                z0[v] += L0 * tj; z1[v] += L1 * tj;
            }
        }
        #pragma unroll 4
        for (int j2 = 0; j2 < 64; ++j2) {
            double L1 = Ad[rB * PAD2 + 64 + j2];
            L1 = (j2 < l) ? L1 : 0.0;
            #pragma unroll
            for (int v = 0; v < 2; ++v) {
                double tj = readlane_d(t1[v], j2);
                z1[v] += L1 * tj;
            }
        }
        double g00 = z0[0]*z0[0] + z1[0]*z1[0];
        double g01 = z0[0]*z0[1] + z1[0]*z1[1];
        double g11 = z0[1]*z0[1] + z1[1]*z1[1];
        #pragma unroll
        for (int o = 32; o > 0; o >>= 1) {
            g00 += __shfl_xor(g00, o);
            g01 += __shfl_xor(g01, o);
            g11 += __shfl_xor(g11, o);
        }
        double dif = g00 - g11;
        double lmin = 0.5 * ((g00 + g11) - sqrt(dif * dif + 4.0 * g01 * g01));
        if (l == 0) dmisc[wid] = lmin;
    }
    __syncthreads();
    if (tid == 0) {
        double lmin = fmin(dmisc[1], fmin(dmisc[2], dmisc[3]));
        conds[b] = sqrt(fmax(dmisc[0], 0.0) / fmax(lmin, 1e-290));
    }
}

__global__ void reduce_kernel(const double* __restrict__ conds, float* __restrict__ out, int B) {
    __shared__ double sred[4];
    int tid = threadIdx.x;
    double acc = 0.0;
    for (int i = tid; i < B; i += 256) acc += conds[i];
    #pragma unroll
    for (int o = 32; o > 0; o >>= 1) acc += __shfl_xor(acc, o);
    if ((tid & 63) == 0) sred[tid >> 6] = acc;
    __syncthreads();
    if (tid == 0) out[0] = (float)((sred[0] + sred[1] + sred[2] + sred[3]) / (double)B);
}

extern "C" void kernel_launch(void* const* d_in, const int* in_sizes, int n_in,
                              void* d_out, int out_size, void* d_ws, size_t ws_size,
                              hipStream_t stream) {
    const float* DD = (const float*)d_in[0];
    const float* LE = (const float*)d_in[1];
    const float* SC = (const float*)d_in[2];
    float* out = (float*)d_out;
    int B = in_sizes[0] / (N * N);
    double* conds = (double*)d_ws;

    static_assert(SMEM_BYTES <= 160 * 1024, "LDS budget");
    (void)hipFuncSetAttribute((const void*)cond_kernel,
                              hipFuncAttributeMaxDynamicSharedMemorySize, (int)SMEM_BYTES);
    hipLaunchKernelGGL(cond_kernel, dim3(B), dim3(NTHREADS), SMEM_BYTES, stream, DD, LE, SC, conds);
    hipLaunchKernelGGL(reduce_kernel, dim3(1), dim3(256), 0, stream, conds, out, B);
}